// Round 5
// baseline (860.443 us; speedup 1.0000x reference)
//
#include <hip/hip_runtime.h>
#include <hip/hip_fp16.h>

#define N_NODES 100000
#define N_EDGESV 1000000
#define N_REL 7
#define IN_CH 128
#define HID_CH 64
#define OUT_CH 2
#define NB 4
#define DI 32
#define DO 16
#define SCAN_CHUNK 1024
#define NCHUNKS ((N_NODES + SCAN_CHUNK - 1) / SCAN_CHUNK)  // 98
#define NEGI -3.0e38f
#define NEGTEST -1.0e38f
#define OFFMASK 0x0FFFFFFF

// ================= CSR build =================
__global__ void hist_kernel(const int* __restrict__ ei, int* __restrict__ deg) {
    int e = blockIdx.x * blockDim.x + threadIdx.x;
    if (e < N_EDGESV) atomicAdd(&deg[ei[N_EDGESV + e]], 1);
}

__global__ void scan1_kernel(const int* __restrict__ deg, int* __restrict__ off,
                             int* __restrict__ sums) {
    __shared__ int lds[256];
    const int tid = threadIdx.x;
    const int base = blockIdx.x * SCAN_CHUNK + tid * 4;
    int v0 = (base + 0 < N_NODES) ? deg[base + 0] : 0;
    int v1 = (base + 1 < N_NODES) ? deg[base + 1] : 0;
    int v2 = (base + 2 < N_NODES) ? deg[base + 2] : 0;
    int v3 = (base + 3 < N_NODES) ? deg[base + 3] : 0;
    int t0 = v0, t1 = v0 + v1, t2 = t1 + v2, t3 = t2 + v3;
    lds[tid] = t3;
    __syncthreads();
    for (int d = 1; d < 256; d <<= 1) {
        int t = (tid >= d) ? lds[tid - d] : 0;
        __syncthreads();
        if (tid >= d) lds[tid] += t;
        __syncthreads();
    }
    int excl = lds[tid] - t3;
    if (base + 0 < N_NODES) off[base + 1] = excl + t0;
    if (base + 1 < N_NODES) off[base + 2] = excl + t1;
    if (base + 2 < N_NODES) off[base + 3] = excl + t2;
    if (base + 3 < N_NODES) off[base + 4] = excl + t3;
    if (tid == 255) sums[blockIdx.x] = lds[255];
}

__global__ void scan2_kernel(int* __restrict__ sums) {
    __shared__ int lds[128];
    int t = threadIdx.x;
    lds[t] = (t < NCHUNKS) ? sums[t] : 0;
    __syncthreads();
    for (int d = 1; d < 128; d <<= 1) {
        int v = (t >= d) ? lds[t - d] : 0;
        __syncthreads();
        if (t >= d) lds[t] += v;
        __syncthreads();
    }
    if (t < NCHUNKS) sums[t] = lds[t];
}

__global__ void scan3_kernel(int* __restrict__ off, const int* __restrict__ sums,
                             int* __restrict__ cursor) {
    int i = blockIdx.x * blockDim.x + threadIdx.x;
    if (i == 0) { off[0] = 0; cursor[0] = 0; }
    if (i < N_NODES) {
        int chunk = i / SCAN_CHUNK;
        int v = off[i + 1] + ((chunk > 0) ? sums[chunk - 1] : 0);
        off[i + 1] = v;
        cursor[i + 1] = v;
    }
}

// packed1: byte offset into msg1 (src*896 + r*128) | r<<28
// packed2: byte offset into msg2 (src*64 + r*8); r = (pk>>3)&7
__global__ void scatter_kernel(const int* __restrict__ ei, const int* __restrict__ et,
                               int* __restrict__ cursor, int* __restrict__ packed1,
                               int* __restrict__ packed2) {
    int e = blockIdx.x * blockDim.x + threadIdx.x;
    if (e < N_EDGESV) {
        int d = ei[N_EDGESV + e];
        int s = ei[e];
        int r = et[e];
        int pos = atomicAdd(&cursor[d], 1);
        packed1[pos] = (s * 896 + r * 128) | (r << 28);
        packed2[pos] = s * 64 + r * 8;
    }
}

// ========== rootmm: hroot = x@root1 + bias1; weights in 128 VGPRs ==========
__global__ __launch_bounds__(256)
void rootmm_kernel(const float* __restrict__ x, const float* __restrict__ root1,
                   const float* __restrict__ bias1, float* __restrict__ hroot)
{
    const int lane = threadIdx.x & 63;  // output channel
    float w[IN_CH];
#pragma unroll
    for (int i = 0; i < IN_CH; ++i) w[i] = root1[i * HID_CH + lane];  // coalesced
    const float bias = bias1[lane];

    const int wid = blockIdx.x * (blockDim.x >> 6) + (threadIdx.x >> 6);
    const int nw = gridDim.x * (blockDim.x >> 6);

    for (int n = wid; n < N_NODES; n += nw) {
        const float4* xr = (const float4*)(x + ((size_t)n << 7));
        float acc = bias;
#pragma unroll
        for (int i4 = 0; i4 < 32; ++i4) {
            float4 xv = xr[i4];  // wave-uniform address -> broadcast
            acc = fmaf(xv.x, w[i4 * 4 + 0], acc);
            acc = fmaf(xv.y, w[i4 * 4 + 1], acc);
            acc = fmaf(xv.z, w[i4 * 4 + 2], acc);
            acc = fmaf(xv.w, w[i4 * 4 + 3], acc);
        }
        hroot[((size_t)n << 6) + lane] = acc;
    }
}

// ========== pre1: msg1[n][r][c] fp16; one relation per block, W in VGPRs ==========
__global__ __launch_bounds__(256)
void pre1_kernel(const float* __restrict__ x, const float* __restrict__ W1,
                 __half* __restrict__ msg1)
{
    const int r = blockIdx.x % N_REL;
    const int lane = threadIdx.x & 63;
    const int b = lane >> 4;
    const int j = lane & 15;

    float w[DI];  // weight column W1[r][b][:, j] in registers
    const float* wp = W1 + ((size_t)(r * NB + b) * DI) * DO + j;
#pragma unroll
    for (int i = 0; i < DI; ++i) w[i] = wp[i * DO];

    const int wid = (blockIdx.x / N_REL) * (blockDim.x >> 6) + (threadIdx.x >> 6);
    const int nw = (gridDim.x / N_REL) * (blockDim.x >> 6);

    for (int n = wid; n < N_NODES; n += nw) {
        const float4* xr = (const float4*)(x + ((size_t)n << 7)) + (b << 3);
        float4 x0 = xr[0], x1 = xr[1], x2 = xr[2], x3 = xr[3];
        float4 x4 = xr[4], x5 = xr[5], x6 = xr[6], x7 = xr[7];
        float m = 0.f;
        m = fmaf(x0.x, w[0], m);  m = fmaf(x0.y, w[1], m);
        m = fmaf(x0.z, w[2], m);  m = fmaf(x0.w, w[3], m);
        m = fmaf(x1.x, w[4], m);  m = fmaf(x1.y, w[5], m);
        m = fmaf(x1.z, w[6], m);  m = fmaf(x1.w, w[7], m);
        m = fmaf(x2.x, w[8], m);  m = fmaf(x2.y, w[9], m);
        m = fmaf(x2.z, w[10], m); m = fmaf(x2.w, w[11], m);
        m = fmaf(x3.x, w[12], m); m = fmaf(x3.y, w[13], m);
        m = fmaf(x3.z, w[14], m); m = fmaf(x3.w, w[15], m);
        m = fmaf(x4.x, w[16], m); m = fmaf(x4.y, w[17], m);
        m = fmaf(x4.z, w[18], m); m = fmaf(x4.w, w[19], m);
        m = fmaf(x5.x, w[20], m); m = fmaf(x5.y, w[21], m);
        m = fmaf(x5.z, w[22], m); m = fmaf(x5.w, w[23], m);
        m = fmaf(x6.x, w[24], m); m = fmaf(x6.y, w[25], m);
        m = fmaf(x6.z, w[26], m); m = fmaf(x6.w, w[27], m);
        m = fmaf(x7.x, w[28], m); m = fmaf(x7.y, w[29], m);
        m = fmaf(x7.z, w[30], m); m = fmaf(x7.w, w[31], m);
        msg1[(size_t)n * (N_REL * HID_CH) + (r << 6) + lane] = __float2half(m);
    }
}

// ========== agg1: wave/node; gather fp16 msgs via byte offsets; fuse relu+msg2 ==========
__global__ __launch_bounds__(256, 6)
void agg1_kernel(const __half* __restrict__ msg1, const float* __restrict__ hroot,
                 const int* __restrict__ off, const int* __restrict__ packed1,
                 const float* __restrict__ comp2, const float* __restrict__ basis2,
                 const float* __restrict__ root2, const float* __restrict__ bias2,
                 float* __restrict__ msg2)
{
    __shared__ float w2[N_REL * 2 * HID_CH];  // [r][o][i], 3.5 KB
    for (int idx = threadIdx.x; idx < N_REL * 2 * HID_CH; idx += blockDim.x) {
        int i = idx & 63;
        int o = (idx >> 6) & 1;
        int r = idx >> 7;
        float v = 0.f;
#pragma unroll
        for (int bb = 0; bb < NB; ++bb)
            v += comp2[r * NB + bb] * basis2[(bb * HID_CH + i) * OUT_CH + o];
        w2[idx] = v;
    }
    __syncthreads();

    const int lane = threadIdx.x & 63;
    const int n = blockIdx.x * (blockDim.x >> 6) + (threadIdx.x >> 6);
    if (n >= N_NODES) return;

    const char* m1 = (const char*)msg1;
    const int lane2 = lane * 2;
    const int st = off[n], en = off[n + 1];
    float a0 = NEGI, a1 = NEGI, a2 = NEGI, a3 = NEGI, a4 = NEGI, a5 = NEGI, a6 = NEGI;

#define SEL(r_, v_) \
    a0 = fmaxf(a0, (r_ == 0) ? v_ : NEGI); \
    a1 = fmaxf(a1, (r_ == 1) ? v_ : NEGI); \
    a2 = fmaxf(a2, (r_ == 2) ? v_ : NEGI); \
    a3 = fmaxf(a3, (r_ == 3) ? v_ : NEGI); \
    a4 = fmaxf(a4, (r_ == 4) ? v_ : NEGI); \
    a5 = fmaxf(a5, (r_ == 5) ? v_ : NEGI); \
    a6 = fmaxf(a6, (r_ == 6) ? v_ : NEGI);

    int p = st;
    for (; p + 3 < en; p += 4) {  // 4 gathers in flight
        unsigned k0 = (unsigned)packed1[p];
        unsigned k1 = (unsigned)packed1[p + 1];
        unsigned k2 = (unsigned)packed1[p + 2];
        unsigned k3 = (unsigned)packed1[p + 3];
        float v0 = __half2float(*(const __half*)(m1 + ((k0 & OFFMASK) + lane2)));
        float v1 = __half2float(*(const __half*)(m1 + ((k1 & OFFMASK) + lane2)));
        float v2 = __half2float(*(const __half*)(m1 + ((k2 & OFFMASK) + lane2)));
        float v3 = __half2float(*(const __half*)(m1 + ((k3 & OFFMASK) + lane2)));
        int r0 = k0 >> 28, r1 = k1 >> 28, r2 = k2 >> 28, r3 = k3 >> 28;
        SEL(r0, v0) SEL(r1, v1) SEL(r2, v2) SEL(r3, v3)
    }
    for (; p < en; ++p) {
        unsigned k0 = (unsigned)packed1[p];
        float v0 = __half2float(*(const __half*)(m1 + ((k0 & OFFMASK) + lane2)));
        int r0 = k0 >> 28;
        SEL(r0, v0)
    }
#undef SEL

    float add = 0.f;
    add += (a0 > NEGTEST) ? a0 : 0.f;
    add += (a1 > NEGTEST) ? a1 : 0.f;
    add += (a2 > NEGTEST) ? a2 : 0.f;
    add += (a3 > NEGTEST) ? a3 : 0.f;
    add += (a4 > NEGTEST) ? a4 : 0.f;
    add += (a5 > NEGTEST) ? a5 : 0.f;
    add += (a6 > NEGTEST) ? a6 : 0.f;

    const float h = fmaxf(hroot[((size_t)n << 6) + lane] + add, 0.f);

    // ---- layer-2 message precompute: 14 dot-products + self term ----
    float o[16];
#pragma unroll
    for (int r = 0; r < N_REL; ++r) {
        float t0 = h * w2[r * 128 + lane];
        float t1 = h * w2[r * 128 + 64 + lane];
#pragma unroll
        for (int s = 32; s > 0; s >>= 1) {
            t0 += __shfl_xor(t0, s);
            t1 += __shfl_xor(t1, s);
        }
        o[r * 2] = t0;
        o[r * 2 + 1] = t1;
    }
    {
        float u0 = h * root2[lane * 2 + 0];
        float u1 = h * root2[lane * 2 + 1];
#pragma unroll
        for (int s = 32; s > 0; s >>= 1) {
            u0 += __shfl_xor(u0, s);
            u1 += __shfl_xor(u1, s);
        }
        o[14] = u0 + bias2[0];
        o[15] = u1 + bias2[1];
    }
    if (lane == 0) {
        float4* dst = (float4*)(msg2 + (size_t)n * 16);
        dst[0] = make_float4(o[0], o[1], o[2], o[3]);
        dst[1] = make_float4(o[4], o[5], o[6], o[7]);
        dst[2] = make_float4(o[8], o[9], o[10], o[11]);
        dst[3] = make_float4(o[12], o[13], o[14], o[15]);
    }
}

// ========== agg2: thread/node; float2 gathers via byte offsets ==========
__global__ __launch_bounds__(256)
void agg2_kernel(const float* __restrict__ msg2, const int* __restrict__ off,
                 const int* __restrict__ packed2, float* __restrict__ out)
{
    const int n = blockIdx.x * blockDim.x + threadIdx.x;
    if (n >= N_NODES) return;
    const char* m2 = (const char*)msg2;
    const int st = off[n], en = off[n + 1];
    float o0 = msg2[(size_t)n * 16 + 14];  // self + bias pre-folded
    float o1 = msg2[(size_t)n * 16 + 15];
    float ax[7], ay[7];
#pragma unroll
    for (int k = 0; k < 7; ++k) { ax[k] = NEGI; ay[k] = NEGI; }
    for (int p = st; p < en; ++p) {
        int pk = packed2[p];
        int r = (pk >> 3) & 7;
        const float2 f = *(const float2*)(m2 + pk);
#pragma unroll
        for (int k = 0; k < 7; ++k) {
            ax[k] = fmaxf(ax[k], (r == k) ? f.x : NEGI);
            ay[k] = fmaxf(ay[k], (r == k) ? f.y : NEGI);
        }
    }
#pragma unroll
    for (int k = 0; k < 7; ++k) {
        o0 += (ax[k] > NEGTEST) ? ax[k] : 0.f;
        o1 += (ay[k] > NEGTEST) ? ay[k] : 0.f;
    }
    out[(size_t)n * OUT_CH + 0] = o0;
    out[(size_t)n * OUT_CH + 1] = o1;
}

extern "C" void kernel_launch(void* const* d_in, const int* in_sizes, int n_in,
                              void* d_out, int out_size, void* d_ws, size_t ws_size,
                              hipStream_t stream)
{
    const float* x      = (const float*)d_in[0];
    const int*   ei     = (const int*)d_in[1];
    const int*   et     = (const int*)d_in[2];
    const float* W1     = (const float*)d_in[3];
    const float* root1  = (const float*)d_in[4];
    const float* bias1  = (const float*)d_in[5];
    const float* comp2  = (const float*)d_in[6];
    const float* basis2 = (const float*)d_in[7];
    const float* root2  = (const float*)d_in[8];
    const float* bias2  = (const float*)d_in[9];
    float* out = (float*)d_out;

    // workspace carve-up (~135 MB)
    char* ws = (char*)d_ws;
    size_t o = 0;
    auto carve = [&](size_t bytes) { char* p = ws + o; o += (bytes + 255) & ~(size_t)255; return p; };
    int*    deg     = (int*)carve(sizeof(int) * N_NODES);
    int*    off     = (int*)carve(sizeof(int) * (N_NODES + 1));
    int*    cursor  = (int*)carve(sizeof(int) * (N_NODES + 1));
    int*    sums    = (int*)carve(sizeof(int) * 128);
    int*    packed1 = (int*)carve(sizeof(int) * N_EDGESV);
    int*    packed2 = (int*)carve(sizeof(int) * N_EDGESV);
    __half* msg1    = (__half*)carve(sizeof(__half) * (size_t)N_NODES * N_REL * HID_CH); // 89.6 MB
    float*  hroot   = (float*)carve(sizeof(float) * (size_t)N_NODES * HID_CH);           // 25.6 MB
    float*  msg2    = (float*)carve(sizeof(float) * (size_t)N_NODES * 16);               //  6.4 MB

    // ---- CSR build ----
    hipMemsetAsync(deg, 0, sizeof(int) * N_NODES, stream);
    hist_kernel<<<(N_EDGESV + 255) / 256, 256, 0, stream>>>(ei, deg);
    scan1_kernel<<<NCHUNKS, 256, 0, stream>>>(deg, off, sums);
    scan2_kernel<<<1, 128, 0, stream>>>(sums);
    scan3_kernel<<<(N_NODES + 255) / 256, 256, 0, stream>>>(off, sums, cursor);
    scatter_kernel<<<(N_EDGESV + 255) / 256, 256, 0, stream>>>(ei, et, cursor, packed1, packed2);

    // ---- dense precomputes (weights in registers, zero LDS) ----
    rootmm_kernel<<<2048, 256, 0, stream>>>(x, root1, bias1, hroot);
    pre1_kernel<<<7 * 256, 256, 0, stream>>>(x, W1, msg1);

    // ---- layer 1 aggregation (+ fused layer-2 message build) ----
    agg1_kernel<<<(N_NODES + 3) / 4, 256, 0, stream>>>(msg1, hroot, off, packed1,
                                                       comp2, basis2, root2, bias2, msg2);

    // ---- layer 2 aggregation ----
    agg2_kernel<<<(N_NODES + 255) / 256, 256, 0, stream>>>(msg2, off, packed2, out);
}